// Round 1
// 615.422 us; speedup vs baseline: 1.2186x; 1.2186x over previous
//
#include <hip/hip_runtime.h>

#define C_ 256
#define T_ 16
#define H_ 64
#define W_ 64
#define PT 5
#define PH 8
#define PW 8
#define OT 4
#define OH 7
#define OW 7
#define SSCALE (1.0f/16.0f)
#define TSCALE 1.0f
#define NP (PT * PH * PW)   /* 320 samples */
#define CG 32               /* channels per roi block */
#define PSTR 321            /* smp row stride: 321 % 32 == 1 -> conflict-free pool reads */

typedef float f4v __attribute__((ext_vector_type(4)));

// ---------------- transpose (B,C,T,H,W) -> (B,T,H,W,C) ----------------
// 64x64 tiles, float4 on both global sides (256B segments per 16 lanes).
__global__ __launch_bounds__(256) void transpose_kernel(const float* __restrict__ f,
                                                        float* __restrict__ ft) {
    __shared__ float tile[64][65];
    const int THW = T_ * H_ * W_;
    int thw0 = blockIdx.x * 64;
    int c0 = blockIdx.y * 64;
    int b = blockIdx.z;
    int l4 = threadIdx.x & 15;   // float4 column
    int row = threadIdx.x >> 4;  // 0..15
#pragma unroll
    for (int k = 0; k < 4; ++k) {
        int c = row + k * 16;
        const f4v* src = reinterpret_cast<const f4v*>(
            &f[((size_t)b * C_ + c0 + c) * THW + thw0 + l4 * 4]);
        f4v v = __builtin_nontemporal_load(src);  // f is streamed once; don't evict ft
        tile[c][l4 * 4 + 0] = v[0];
        tile[c][l4 * 4 + 1] = v[1];
        tile[c][l4 * 4 + 2] = v[2];
        tile[c][l4 * 4 + 3] = v[3];
    }
    __syncthreads();
#pragma unroll
    for (int k = 0; k < 4; ++k) {
        int t = row + k * 16;
        f4v v;
        v[0] = tile[l4 * 4 + 0][t];
        v[1] = tile[l4 * 4 + 1][t];
        v[2] = tile[l4 * 4 + 2][t];
        v[3] = tile[l4 * 4 + 3][t];
        *reinterpret_cast<f4v*>(&ft[((size_t)b * THW + thw0 + t) * C_ + c0 + l4 * 4]) = v;
    }
}

// ---------------- main: one block per (roi, 32-channel group) ----------------
// 8 float4-lanes (32 ch) x 32 samples per iteration; 10 iterations cover 320 samples.
__global__ __launch_bounds__(256) void roi_kernel(const float* __restrict__ ft,
                                                  const float* __restrict__ rois,
                                                  float* __restrict__ out) {
    __shared__ float smp[CG][PSTR];  // [channel][sample]
    __shared__ float sroi[7];
    __shared__ int s_lo[21], s_hi[21];
    __shared__ float s_fr[21], s_vd[21];

    int r = blockIdx.y;
    int c0 = blockIdx.x * CG;

    if (threadIdx.x < 7) sroi[threadIdx.x] = rois[r * 7 + threadIdx.x];
    __syncthreads();

    if (threadIdx.x < 21) {
        int i = threadIdx.x;
        float start, end, size;
        int j, n;
        if (i < 5) {
            j = i; n = PT;
            start = sroi[5] * TSCALE; end = sroi[6] * TSCALE; size = (float)T_;
        } else if (i < 13) {
            j = i - 5; n = PH;
            start = sroi[2] * SSCALE; end = sroi[4] * SSCALE; size = (float)H_;
        } else {
            j = i - 13; n = PW;
            start = sroi[1] * SSCALE; end = sroi[3] * SSCALE; size = (float)W_;
        }
        float length = fmaxf(end - start + 1.0f, 1.0f);
        float step = length / (float)(n - 1);
        float coord = start + step * (float)j;
        float valid = (coord >= 0.0f && coord < size) ? 1.0f : 0.0f;
        float lo = fminf(fmaxf(floorf(coord), 0.0f), size - 1.0f);
        s_lo[i] = (int)lo;
        s_hi[i] = min((int)lo + 1, (int)size - 1);
        s_fr[i] = coord - lo;
        s_vd[i] = valid;
    }
    __syncthreads();

    int b = (int)sroi[0];
    int c4 = threadIdx.x & 7;    // float4 lane within 32-channel group
    int psub = threadIdx.x >> 3; // 0..31 sample slot
    const int CQ = C_ / 4;       // 64 float4 per position
    const f4v* fb = reinterpret_cast<const f4v*>(ft)
                  + (size_t)b * (T_ * H_ * W_) * CQ + (c0 >> 2) + c4;

    // phase 2: 320 trilinear samples x 32 channels (4 per thread)
#pragma unroll 2
    for (int it = 0; it < NP / 32; ++it) {
        int p = it * 32 + psub;
        int ti = p >> 6;
        int yi = (p >> 3) & 7;
        int xi = p & 7;
        int tl = s_lo[ti], th = s_hi[ti];
        float tf = s_fr[ti];
        int yl = s_lo[5 + yi], yh = s_hi[5 + yi];
        float fy = s_fr[5 + yi];
        int xl = s_lo[13 + xi], xh = s_hi[13 + xi];
        float fx = s_fr[13 + xi];
        float mask = s_vd[ti] * s_vd[5 + yi] * s_vd[13 + xi];

        int r_tl_yl = (tl * H_ + yl) * W_;
        int r_tl_yh = (tl * H_ + yh) * W_;
        int r_th_yl = (th * H_ + yl) * W_;
        int r_th_yh = (th * H_ + yh) * W_;

        f4v v000 = fb[(r_tl_yl + xl) * CQ];
        f4v v001 = fb[(r_tl_yl + xh) * CQ];
        f4v v010 = fb[(r_tl_yh + xl) * CQ];
        f4v v011 = fb[(r_tl_yh + xh) * CQ];
        f4v v100 = fb[(r_th_yl + xl) * CQ];
        f4v v101 = fb[(r_th_yl + xh) * CQ];
        f4v v110 = fb[(r_th_yh + xl) * CQ];
        f4v v111 = fb[(r_th_yh + xh) * CQ];

        f4v vx00 = v000 + fx * (v001 - v000);
        f4v vx01 = v010 + fx * (v011 - v010);
        f4v vx10 = v100 + fx * (v101 - v100);
        f4v vx11 = v110 + fx * (v111 - v110);
        f4v vy0 = vx00 + fy * (vx01 - vx00);
        f4v vy1 = vx10 + fy * (vx11 - vx10);
        f4v v = vy0 + tf * (vy1 - vy0);
        v *= mask;

        int cb = c4 * 4;
        smp[cb + 0][p] = v[0];
        smp[cb + 1][p] = v[1];
        smp[cb + 2][p] = v[2];
        smp[cb + 3][p] = v[3];
    }
    __syncthreads();

    // phase 3: 2x2x2 avg pool; smp[c][pos] layout -> conflict-free reads,
    // contiguous coalesced NT stores (don't evict ft from L3).
    const int NOUT = CG * OT * OH * OW;  // 6272
    float* outc = out + ((size_t)r * C_ + c0) * (OT * OH * OW);
    for (int ov = 0; ov < (NOUT + 255) / 256; ++ov) {
        int o = ov * 256 + threadIdx.x;
        if (o < NOUT) {
            int cc = o / 196;
            int pos = o - cc * 196;
            int t = pos / 49;
            int rem = pos - t * 49;
            int h = rem / 7;
            int w = rem - h * 7;
            const float* s0 = &smp[cc][t * 64 + h * 8 + w];
            float s = s0[0] + s0[1] + s0[8] + s0[9] + s0[64] + s0[65] + s0[72] + s0[73];
            __builtin_nontemporal_store(s * 0.125f, &outc[o]);
        }
    }
}

// ---------------- fallback: direct gather, one thread per output ----------------
__device__ __forceinline__ void axis_sample(float start, float end, float size, int n,
                                            int j, int& lo_i, int& hi_i, float& frac,
                                            float& valid) {
    float length = fmaxf(end - start + 1.0f, 1.0f);
    float step = length / (float)(n - 1);
    float coord = start + step * (float)j;
    valid = (coord >= 0.0f && coord < size) ? 1.0f : 0.0f;
    float lo = fminf(fmaxf(floorf(coord), 0.0f), size - 1.0f);
    frac = coord - lo;
    lo_i = (int)lo;
    hi_i = min(lo_i + 1, (int)size - 1);
}

__global__ void roi_direct(const float* __restrict__ f, const float* __restrict__ rois,
                           float* __restrict__ out, long long total) {
    long long idx = (long long)blockIdx.x * 256 + threadIdx.x;
    if (idx >= total) return;
    int w = (int)(idx % OW);
    long long q = idx / OW;
    int h = (int)(q % OH);
    q /= OH;
    int t = (int)(q % OT);
    q /= OT;
    int c = (int)(q % C_);
    int r = (int)(q / C_);

    float rb = rois[r * 7 + 0];
    float x1 = rois[r * 7 + 1] * SSCALE;
    float y1 = rois[r * 7 + 2] * SSCALE;
    float x2 = rois[r * 7 + 3] * SSCALE;
    float y2 = rois[r * 7 + 4] * SSCALE;
    float t1 = rois[r * 7 + 5] * TSCALE;
    float t2 = rois[r * 7 + 6] * TSCALE;
    int b = (int)rb;
    const float* fc = f + ((size_t)b * C_ + c) * (T_ * H_ * W_);

    float acc = 0.0f;
    for (int dt = 0; dt < 2; ++dt) {
        int tlo, thi; float tf, tv;
        axis_sample(t1, t2, (float)T_, PT, t + dt, tlo, thi, tf, tv);
        for (int dh = 0; dh < 2; ++dh) {
            int ylo, yhi; float yf, yv;
            axis_sample(y1, y2, (float)H_, PH, h + dh, ylo, yhi, yf, yv);
            for (int dw = 0; dw < 2; ++dw) {
                int xlo, xhi; float xf, xv;
                axis_sample(x1, x2, (float)W_, PW, w + dw, xlo, xhi, xf, xv);
                float v000 = fc[(tlo * H_ + ylo) * W_ + xlo];
                float v001 = fc[(tlo * H_ + ylo) * W_ + xhi];
                float v010 = fc[(tlo * H_ + yhi) * W_ + xlo];
                float v011 = fc[(tlo * H_ + yhi) * W_ + xhi];
                float v100 = fc[(thi * H_ + ylo) * W_ + xlo];
                float v101 = fc[(thi * H_ + ylo) * W_ + xhi];
                float v110 = fc[(thi * H_ + yhi) * W_ + xlo];
                float v111 = fc[(thi * H_ + yhi) * W_ + xhi];
                float vx00 = v000 + xf * (v001 - v000);
                float vx01 = v010 + xf * (v011 - v010);
                float vx10 = v100 + xf * (v101 - v100);
                float vx11 = v110 + xf * (v111 - v110);
                float vy0 = vx00 + yf * (vx01 - vx00);
                float vy1 = vx10 + yf * (vx11 - vx10);
                float v = vy0 + tf * (vy1 - vy0);
                acc += v * (tv * yv * xv);
            }
        }
    }
    out[idx] = acc * 0.125f;
}

extern "C" void kernel_launch(void* const* d_in, const int* in_sizes, int n_in,
                              void* d_out, int out_size, void* d_ws, size_t ws_size,
                              hipStream_t stream) {
    const float* feat = (const float*)d_in[0];
    const float* rois = (const float*)d_in[1];
    float* out = (float*)d_out;
    int nroi = in_sizes[1] / 7;
    int B = in_sizes[0] / (C_ * T_ * H_ * W_);
    size_t need = (size_t)B * T_ * H_ * W_ * C_ * sizeof(float);

    if (ws_size >= need) {
        dim3 g1(T_ * H_ * W_ / 64, C_ / 64, B);
        transpose_kernel<<<g1, 256, 0, stream>>>(feat, (float*)d_ws);
        dim3 g2(C_ / CG, nroi);
        roi_kernel<<<g2, 256, 0, stream>>>((const float*)d_ws, rois, out);
    } else {
        long long total = (long long)nroi * C_ * OT * OH * OW;
        roi_direct<<<(int)((total + 255) / 256), 256, 0, stream>>>(feat, rois, out, total);
    }
}